// Round 15
// baseline (105.320 us; speedup 1.0000x reference)
//
#include <hip/hip_runtime.h>

#define SEQ 2048
#define HDIM 64
#define NH 16
#define EMB 1024

typedef __attribute__((ext_vector_type(8))) short bf16x8;
typedef __attribute__((ext_vector_type(4))) float f32x4;
typedef __attribute__((ext_vector_type(16))) float f32x16;

static __device__ __forceinline__ unsigned short f2bf(float f) {
  unsigned int u = __builtin_bit_cast(unsigned int, f);
  u += 0x7FFF + ((u >> 16) & 1);  // round-to-nearest-even
  return (unsigned short)(u >> 16);
}

// ---------------- fused fp32 -> bf16 convert: x | Wq | Wk | Wv in one launch ----------------
__global__ void cvt_all(const float* __restrict__ x, const float* __restrict__ Wq,
                        const float* __restrict__ Wk, const float* __restrict__ Wv,
                        unsigned short* __restrict__ xb, unsigned short* __restrict__ wb) {
  const int NX = 2 * SEQ * EMB;        // 4M
  const int NW = EMB * EMB;            // 1M
  int i = (blockIdx.x * blockDim.x + threadIdx.x) * 4;
  const float* src;
  unsigned short* dst;
  if (i < NX)                { src = x  + i;                 dst = xb + i; }
  else if (i < NX + NW)      { src = Wq + (i - NX);          dst = wb + (i - NX); }
  else if (i < NX + 2 * NW)  { src = Wk + (i - NX - NW);     dst = wb + (i - NX); }
  else if (i < NX + 3 * NW)  { src = Wv + (i - NX - 2 * NW); dst = wb + (i - NX); }
  else return;
  float4 v = *(const float4*)src;
  ushort4 o;
  o.x = f2bf(v.x); o.y = f2bf(v.y); o.z = f2bf(v.z); o.w = f2bf(v.w);
  *(ushort4*)dst = o;
}

// ---------------- QKV projection GEMM: 128x64 tile, 3-buf counted-vmcnt, 1536 blocks ----------------
// R14 falsified the traffic theory (FETCH down, time flat). Session data: TLP wins, depth
// is null. 128x64 tile -> grid 1536 (6/CU demand), LDS 36KB -> 4 blocks/CU RESIDENT
// (16 waves/CU, 50%) vs R13's 3 (37.5%). R11's 128x64 failure was the exposed
// stage->drain->read ordering; this keeps R13's proven counted-vmcnt pipeline.
// Epilogue: z==0 (Q) prescaled by C1; z==2 (V^T) key-cols swizzled (bit2<->3) for attn.
__global__ __launch_bounds__(256) void qkv_gemm(
    const unsigned short* __restrict__ xb,
    const unsigned short* __restrict__ wb,   // [3][1024][1024]
    const float* __restrict__ bq, const float* __restrict__ bk, const float* __restrict__ bv,
    unsigned short* __restrict__ qout, unsigned short* __restrict__ kout,
    unsigned short* __restrict__ vtout)
{
  __shared__ unsigned short As[3][128 * 32];
  __shared__ unsigned short Bs[3][64 * 32];
  // XCD-chunked decode: 1536 blocks, bid&7 = XCD. Per XCD: 192 blocks = 4 chunks x 48.
  // Chunk = {8 m-tiles x 6 strips}; strip = z*16 + n-tile. Working set ~2.75MB <= L2.
  const int bid = blockIdx.x;
  const int xg = bid & 7, jj0 = bid >> 3;     // per-XCD sequence 0..191
  const int cl = jj0 / 48, kk = jj0 % 48;     // chunk-local 0..3, block-in-chunk 0..47
  const int chunk = xg * 4 + cl;              // 0..31
  const int mg = chunk >> 3, sg = chunk & 7;  // m-group 0..3, strip-group 0..7
  const int mt = mg * 8 + (kk & 7);           // m-tile 0..31
  const int strip = sg * 6 + (kk >> 3);       // 0..47
  const int z = strip >> 4;                   // 0..2
  const int m0 = mt * 128, n0 = (strip & 15) * 64;

  const unsigned short* Bw = wb + (size_t)z * (EMB * EMB);
  const int tid = threadIdx.x;
  const int w = tid >> 6, l = tid & 63;
  const int wr = w >> 1, wc = w & 1;
  const int lc = l & 15, lg = l >> 4;
  const int NK = EMB / 32;   // 32 K-iterations

  f32x4 acc[4][2] = {};

  auto stage = [&](int buf, int kb) {   // 3 global_load_lds per thread (A:2, B:1)
#pragma unroll
    for (int c = 0; c < 2; ++c) {
      int elem = c * 2048 + w * 512 + l * 8;
      int row = elem >> 5, col = elem & 31;
      __builtin_amdgcn_global_load_lds(
          (const __attribute__((address_space(1))) void*)(xb + (size_t)(m0 + row) * EMB + kb + col),
          (__attribute__((address_space(3))) void*)(&As[buf][c * 2048 + w * 512]), 16, 0, 0);
    }
    {
      int elem = w * 512 + l * 8;
      int row = elem >> 5, col = elem & 31;
      __builtin_amdgcn_global_load_lds(
          (const __attribute__((address_space(1))) void*)(Bw + (size_t)(n0 + row) * EMB + kb + col),
          (__attribute__((address_space(3))) void*)(&Bs[buf][w * 512]), 16, 0, 0);
    }
  };

  // prologue: tiles 0 and 1 in flight (6 loads)
  stage(0, 0);
  stage(1, 32);

  int cur = 0;
  for (int t = 0; t < NK; ++t) {
    // wait OWN tile-t loads only (tile t+1 stays in flight), then sync all waves.
    if (t + 1 < NK) {
      asm volatile("s_waitcnt vmcnt(3)" ::: "memory");
    } else {
      asm volatile("s_waitcnt vmcnt(0)" ::: "memory");
    }
    __builtin_amdgcn_s_barrier();          // raw barrier: no compiler-inserted drain
    __builtin_amdgcn_sched_barrier(0);     // fence: no hoisting of reads above the wait
    bf16x8 am[4], bn[2];
#pragma unroll
    for (int i = 0; i < 4; ++i)
      am[i] = *(const bf16x8*)(&As[cur][(wr * 64 + i * 16 + lc) * 32 + lg * 8]);
#pragma unroll
    for (int j = 0; j < 2; ++j)
      bn[j] = *(const bf16x8*)(&Bs[cur][(wc * 32 + j * 16 + lc) * 32 + lg * 8]);
    // refill the buffer freed at iter t-1 (reads done before this iter's barrier)
    if (t + 2 < NK) {
      int nb = cur + 2; if (nb >= 3) nb -= 3;
      stage(nb, (t + 2) * 32);
    }
#pragma unroll
    for (int i = 0; i < 4; ++i)
#pragma unroll
      for (int j = 0; j < 2; ++j)
        acc[i][j] = __builtin_amdgcn_mfma_f32_16x16x32_bf16(am[i], bn[j], acc[i][j], 0, 0, 0);
    ++cur; if (cur >= 3) cur = 0;
  }

  const float* bias = (z == 0) ? bq : (z == 1) ? bk : bv;
  const float qscale = 0.03125f * 1.44269504f;   // 1/sqrt(EMB) * log2(e)
  for (int i = 0; i < 4; ++i)
    for (int j = 0; j < 2; ++j)
      for (int r = 0; r < 4; ++r) {
        int m = m0 + wr * 64 + i * 16 + lg * 4 + r;
        int n = n0 + wc * 32 + j * 16 + lc;
        float v = acc[i][j][r] + bias[n];
        if (z == 0) v *= qscale;
        unsigned short o16 = f2bf(v);
        int b = m >> 11, s = m & 2047, h = n >> 6, d = n & 63;
        if (z == 2) {
          int sz = (s & ~12) | ((s & 4) << 1) | ((s & 8) >> 1);  // swap bits 2<->3
          vtout[(((size_t)b * NH + h) * HDIM + d) * SEQ + sz] = o16;
        } else {
          unsigned short* dst = (z == 0) ? qout : kout;
          dst[(((size_t)b * NH + h) * SEQ + s) * HDIM + d] = o16;
        }
      }
}

// ---------------- flash attention: 8 waves = 2 key-halves x 4 q-subtiles ----------------
// VALU-lean body: Q prescaled (no per-score mul), static softmax max (|s|<~1.5, no
// overflow), denominator via ones-MFMA (matrix pipe), P->bf16 via v_cvt_pk_bf16_f32,
// NO cross-lane exchange (V^T key columns pre-swizzled to match P's natural layout).
__global__ __launch_bounds__(512, 4) void attn(
    const unsigned short* __restrict__ Q,   // [BH][S][64], prescaled by C1
    const unsigned short* __restrict__ K,   // [BH][S][64]
    const unsigned short* __restrict__ VT,  // [BH][64][S], key-swizzled
    float* __restrict__ out)                // [B][S][1024]
{
  __shared__ __align__(16) unsigned char ldsraw[34816];  // staging 32KB | merge (aliased)
  const int g = blockIdx.x;                  // 512 blocks
  const int xcd = g & 7, j0 = g >> 3;        // XCD heuristic: 4 heads per XCD group
  const int bh = xcd * 4 + (j0 >> 4);
  const int qt = j0 & 15;                    // q-tile (128 queries)
  const int b = bh >> 4, h = bh & 15;
  const int tid = threadIdx.x;
  const int half = tid >> 8;                 // key-half
  const int wv4 = (tid >> 6) & 3;            // q-subtile within tile
  const int l = tid & 63;
  const int q = l & 31;                      // query column AND key/d row index
  const int hh = l >> 5;
  const int q0 = qt * 128 + wv4 * 32;
  const int NBLK = (SEQ / 2) / 32;           // 32 stages per wave

  unsigned short* kv0 = (unsigned short*)ldsraw + half * 8192;
  unsigned short* kv1 = kv0 + 4096;

  const unsigned short* Qp = Q + ((size_t)bh * SEQ + q0) * HDIM;
  const unsigned short* Kp = K + ((size_t)bh * SEQ + (size_t)half * (SEQ / 2)) * HDIM;
  const unsigned short* Vp = VT + (size_t)bh * HDIM * SEQ + (size_t)half * (SEQ / 2);

  bf16x8 qf[4];   // Q as B-operand: B[k=d][col=q], d = c*16 + hh*8 + j
#pragma unroll
  for (int c = 0; c < 4; ++c)
    qf[c] = *(const bf16x8*)(Qp + q * HDIM + c * 16 + hh * 8);

  // ones A-fragment for the denominator MFMA
  uint4 onesu = make_uint4(0x3F803F80u, 0x3F803F80u, 0x3F803F80u, 0x3F803F80u);
  bf16x8 onesf = __builtin_bit_cast(bf16x8, onesu);

  f32x16 oa = {}, ob = {}, ls = {};
  const bool maskh = (qt == 0) && (wv4 == 0) && (half == 0);
  const bool maskt = (qt == 15) && (wv4 == 3) && (half == 1);

  // Stage one 32-key tile (K 4KB + V 4KB) cooperatively across the half's 4 waves.
  auto stage = [&](unsigned short* buf, int kbase) {
    __builtin_amdgcn_global_load_lds(
        (const __attribute__((address_space(1))) void*)(Kp + (size_t)(kbase + q) * HDIM + wv4 * 16 + hh * 8),
        (__attribute__((address_space(3))) void*)(buf + wv4 * 512), 16, 0, 0);
    __builtin_amdgcn_global_load_lds(
        (const __attribute__((address_space(1))) void*)(Vp + (size_t)((wv4 >> 1) * 32 + q) * SEQ + kbase + (wv4 & 1) * 16 + hh * 8),
        (__attribute__((address_space(3))) void*)(buf + 2048 + wv4 * 512), 16, 0, 0);
  };

  auto body = [&](const bf16x8* kf, const bf16x8* vf, int t) {
    f32x16 s = {};
#pragma unroll
    for (int c = 0; c < 4; ++c)
      s = __builtin_amdgcn_mfma_f32_32x32x16_bf16(kf[c], qf[c], s, 0, 0, 0);
    // corner mask (scores already in log2 domain; exp2(-1e30) = 0)
    if (maskh && t == 0 && q < 8) {
      s[0] = -1e30f; s[1] = -1e30f; s[2] = -1e30f; s[3] = -1e30f;
    }
    if (maskt && t == NBLK - 1 && q >= 24) {
      s[12] = -1e30f; s[13] = -1e30f; s[14] = -1e30f; s[15] = -1e30f;
    }
    float e[16];
#pragma unroll
    for (int jj = 0; jj < 16; ++jj)
      e[jj] = __builtin_amdgcn_exp2f(s[jj]);
    // P -> bf16 pairs via hardware pack (RNE): lo = e[2jj], hi = e[2jj+1]
    unsigned int P[8];
#pragma unroll
    for (int jj = 0; jj < 8; ++jj)
      asm("v_cvt_pk_bf16_f32 %0, %1, %2" : "=v"(P[jj]) : "v"(e[2 * jj]), "v"(e[2 * jj + 1]));
    // no exchange: k-slot s holds key sigma(s) (bit2<->bit3); V^T columns pre-swizzled to match
    uint4 u0q = make_uint4(P[0], P[1], P[2], P[3]);
    uint4 u1q = make_uint4(P[4], P[5], P[6], P[7]);
    bf16x8 pb0 = __builtin_bit_cast(bf16x8, u0q);
    bf16x8 pb1 = __builtin_bit_cast(bf16x8, u1q);
    oa = __builtin_amdgcn_mfma_f32_32x32x16_bf16(vf[0], pb0, oa, 0, 0, 0);
    oa = __builtin_amdgcn_mfma_f32_32x32x16_bf16(vf[1], pb1, oa, 0, 0, 0);
    ob = __builtin_amdgcn_mfma_f32_32x32x16_bf16(vf[2], pb0, ob, 0, 0, 0);
    ob = __builtin_amdgcn_mfma_f32_32x32x16_bf16(vf[3], pb1, ob, 0, 0, 0);
    ls = __builtin_amdgcn_mfma_f32_32x32x16_bf16(onesf, pb0, ls, 0, 0, 0);  // denom
    ls = __builtin_amdgcn_mfma_f32_32x32x16_bf16(onesf, pb1, ls, 0, 0, 0);
  };

  // prologue: tile 0 staged and landed
  stage(kv0, 0);
  asm volatile("s_waitcnt vmcnt(0)" ::: "memory");
  __syncthreads();

  for (int t = 0; t < NBLK; ++t) {
    unsigned short* cur = (t & 1) ? kv1 : kv0;
    if (t + 1 < NBLK) stage((t & 1) ? kv0 : kv1, (t + 1) * 32);  // issue next-tile loads first
    bf16x8 kf[4], vf[4];
#pragma unroll
    for (int c = 0; c < 4; ++c) kf[c] = *(const bf16x8*)(cur + c * 512 + l * 8);
#pragma unroll
    for (int c = 0; c < 4; ++c) vf[c] = *(const bf16x8*)(cur + 2048 + c * 512 + l * 8);
    body(kf, vf, t);
    asm volatile("s_waitcnt vmcnt(0)" ::: "memory");  // next tile landed
    __syncthreads();                                   // all waves done reading cur
  }

  // denominator: every reg of ls = sum over this half's keys for query q (ones-MFMA)
  float lrt = ls[0];

  // merge halves: pure sum (static max). half 1 writes partials; half 0 combines.
  float* smf = (float*)ldsraw;   // staging fully drained by final loop sync
  if (half == 1) {
    float* p = smf + ((size_t)wv4 * 64 + l) * 33;
#pragma unroll
    for (int j = 0; j < 16; ++j) { p[j] = oa[j]; p[16 + j] = ob[j]; }
    p[32] = lrt;
  }
  __syncthreads();
  if (half == 0) {
    const float* p = smf + ((size_t)wv4 * 64 + l) * 33;
    float inv = __builtin_amdgcn_rcpf(lrt + p[32]);
    float* outp = out + ((size_t)b * SEQ + q0 + q) * EMB + h * HDIM;
#pragma unroll
    for (int qd = 0; qd < 4; ++qd) {   // regs 4qd..4qd+3 -> d = 8qd + 4hh + 0..3
      float4 sa = {(oa[4 * qd] + p[4 * qd]) * inv,
                   (oa[4 * qd + 1] + p[4 * qd + 1]) * inv,
                   (oa[4 * qd + 2] + p[4 * qd + 2]) * inv,
                   (oa[4 * qd + 3] + p[4 * qd + 3]) * inv};
      *(float4*)(outp + 8 * qd + 4 * hh) = sa;
      float4 sb = {(ob[4 * qd] + p[16 + 4 * qd]) * inv,
                   (ob[4 * qd + 1] + p[16 + 4 * qd + 1]) * inv,
                   (ob[4 * qd + 2] + p[16 + 4 * qd + 2]) * inv,
                   (ob[4 * qd + 3] + p[16 + 4 * qd + 3]) * inv};
      *(float4*)(outp + 32 + 8 * qd + 4 * hh) = sb;
    }
  }
}

extern "C" void kernel_launch(void* const* d_in, const int* in_sizes, int n_in,
                              void* d_out, int out_size, void* d_ws, size_t ws_size,
                              hipStream_t stream) {
  const float* x  = (const float*)d_in[0];
  const float* Wq = (const float*)d_in[1];
  const float* bq = (const float*)d_in[2];
  const float* Wk = (const float*)d_in[3];
  const float* bk = (const float*)d_in[4];
  const float* Wv = (const float*)d_in[5];
  const float* bv = (const float*)d_in[6];
  // d_in[7] = global_bias: per-head scalar, uniform over key axis -> softmax-invariant, dropped.
  float* out = (float*)d_out;

  char* ws = (char*)d_ws;
  unsigned short* xb   = (unsigned short*)(ws);
  unsigned short* wb   = (unsigned short*)(ws + (8u  << 20));
  unsigned short* qb   = (unsigned short*)(ws + (14u << 20));
  unsigned short* kbuf = (unsigned short*)(ws + (22u << 20));
  unsigned short* vtb  = (unsigned short*)(ws + (30u << 20));

  // 7M elements / 4 per thread / 256 per block
  cvt_all<<<7168, 256, 0, stream>>>(x, Wq, Wk, Wv, xb, wb);
  qkv_gemm<<<dim3(1536), 256, 0, stream>>>(xb, wb, bq, bk, bv, qb, kbuf, vtb);
  attn<<<dim3(512), 512, 0, stream>>>(qb, kbuf, vtb, out);
}

// Round 17
// 99.742 us; speedup vs baseline: 1.0559x; 1.0559x over previous
//
#include <hip/hip_runtime.h>

#define SEQ 2048
#define HDIM 64
#define NH 16
#define EMB 1024

typedef __attribute__((ext_vector_type(8))) short bf16x8;
typedef __attribute__((ext_vector_type(4))) float f32x4;
typedef __attribute__((ext_vector_type(16))) float f32x16;

static __device__ __forceinline__ unsigned short f2bf(float f) {
  unsigned int u = __builtin_bit_cast(unsigned int, f);
  u += 0x7FFF + ((u >> 16) & 1);  // round-to-nearest-even
  return (unsigned short)(u >> 16);
}

// ---------------- fused fp32 -> bf16 convert: x | Wq | Wk | Wv in one launch ----------------
__global__ void cvt_all(const float* __restrict__ x, const float* __restrict__ Wq,
                        const float* __restrict__ Wk, const float* __restrict__ Wv,
                        unsigned short* __restrict__ xb, unsigned short* __restrict__ wb) {
  const int NX = 2 * SEQ * EMB;        // 4M
  const int NW = EMB * EMB;            // 1M
  int i = (blockIdx.x * blockDim.x + threadIdx.x) * 4;
  const float* src;
  unsigned short* dst;
  if (i < NX)                { src = x  + i;                 dst = xb + i; }
  else if (i < NX + NW)      { src = Wq + (i - NX);          dst = wb + (i - NX); }
  else if (i < NX + 2 * NW)  { src = Wk + (i - NX - NW);     dst = wb + (i - NX); }
  else if (i < NX + 3 * NW)  { src = Wv + (i - NX - 2 * NW); dst = wb + (i - NX); }
  else return;
  float4 v = *(const float4*)src;
  ushort4 o;
  o.x = f2bf(v.x); o.y = f2bf(v.y); o.z = f2bf(v.z); o.w = f2bf(v.w);
  *(ushort4*)dst = o;
}

// ---------------- QKV projection GEMM: 128x128, counted-vmcnt + XCD-chunked (R14-green) ----------------
// 3-buffer counted vmcnt(4) + raw s_barrier; XCD-chunked decode (2.75MB/chunk L2-resident).
// Epilogue: z==0 (Q) prescaled by C1; z==2 (V^T) key-cols swizzled (bit2<->3) for attn.
__global__ __launch_bounds__(256) void qkv_gemm(
    const unsigned short* __restrict__ xb,
    const unsigned short* __restrict__ wb,   // [3][1024][1024]
    const float* __restrict__ bq, const float* __restrict__ bk, const float* __restrict__ bv,
    unsigned short* __restrict__ qout, unsigned short* __restrict__ kout,
    unsigned short* __restrict__ vtout)
{
  __shared__ unsigned short As[3][128 * 32];
  __shared__ unsigned short Bs[3][128 * 32];
  const int bid = blockIdx.x;
  const int xg = bid & 7, jj0 = bid >> 3;    // per-XCD sequence 0..95
  const int cl = jj0 / 24, kk = jj0 % 24;    // chunk-local 0..3, block-in-chunk 0..23
  const int chunk = xg * 4 + cl;             // 0..31
  const int mg = chunk >> 3, sg = chunk & 7; // m-group 0..3, strip-group 0..7
  const int mt = mg * 8 + (kk & 7);          // m-tile 0..31
  const int strip = sg * 3 + (kk >> 3);      // 0..23
  const int z = strip >> 3;                  // 0..2
  const int m0 = mt * 128, n0 = (strip & 7) * 128;

  const unsigned short* Bw = wb + (size_t)z * (EMB * EMB);
  const int tid = threadIdx.x;
  const int w = tid >> 6, l = tid & 63;
  const int wr = w >> 1, wc = w & 1;
  const int lc = l & 15, lg = l >> 4;
  const int NK = EMB / 32;   // 32 K-iterations

  f32x4 acc[4][4] = {};

  auto stage = [&](int buf, int kb) {   // 4 global_load_lds per thread
#pragma unroll
    for (int c = 0; c < 2; ++c) {
      int elem = c * 2048 + w * 512 + l * 8;
      int row = elem >> 5, col = elem & 31;
      __builtin_amdgcn_global_load_lds(
          (const __attribute__((address_space(1))) void*)(xb + (size_t)(m0 + row) * EMB + kb + col),
          (__attribute__((address_space(3))) void*)(&As[buf][c * 2048 + w * 512]), 16, 0, 0);
      __builtin_amdgcn_global_load_lds(
          (const __attribute__((address_space(1))) void*)(Bw + (size_t)(n0 + row) * EMB + kb + col),
          (__attribute__((address_space(3))) void*)(&Bs[buf][c * 2048 + w * 512]), 16, 0, 0);
    }
  };

  // prologue: tiles 0 and 1 in flight (8 loads)
  stage(0, 0);
  stage(1, 32);

  int cur = 0;
  for (int t = 0; t < NK; ++t) {
    if (t + 1 < NK) {
      asm volatile("s_waitcnt vmcnt(4)" ::: "memory");
    } else {
      asm volatile("s_waitcnt vmcnt(0)" ::: "memory");
    }
    __builtin_amdgcn_s_barrier();          // raw barrier: no compiler-inserted drain
    __builtin_amdgcn_sched_barrier(0);     // fence: no hoisting of reads above the wait
    bf16x8 am[4], bn[4];
#pragma unroll
    for (int i = 0; i < 4; ++i) {
      am[i] = *(const bf16x8*)(&As[cur][(wr * 64 + i * 16 + lc) * 32 + lg * 8]);
      bn[i] = *(const bf16x8*)(&Bs[cur][(wc * 64 + i * 16 + lc) * 32 + lg * 8]);
    }
    if (t + 2 < NK) {
      int nb = cur + 2; if (nb >= 3) nb -= 3;
      stage(nb, (t + 2) * 32);
    }
#pragma unroll
    for (int i = 0; i < 4; ++i)
#pragma unroll
      for (int j = 0; j < 4; ++j)
        acc[i][j] = __builtin_amdgcn_mfma_f32_16x16x32_bf16(am[i], bn[j], acc[i][j], 0, 0, 0);
    ++cur; if (cur >= 3) cur = 0;
  }

  const float* bias = (z == 0) ? bq : (z == 1) ? bk : bv;
  const float qscale = 0.03125f * 1.44269504f;   // 1/sqrt(EMB) * log2(e)
  for (int i = 0; i < 4; ++i)
    for (int j = 0; j < 4; ++j)
      for (int r = 0; r < 4; ++r) {
        int m = m0 + wr * 64 + i * 16 + lg * 4 + r;
        int n = n0 + wc * 64 + j * 16 + lc;
        float v = acc[i][j][r] + bias[n];
        if (z == 0) v *= qscale;
        unsigned short o16 = f2bf(v);
        int b = m >> 11, s = m & 2047, h = n >> 6, d = n & 63;
        if (z == 2) {
          int sz = (s & ~12) | ((s & 4) << 1) | ((s & 8) >> 1);  // swap bits 2<->3
          vtout[(((size_t)b * NH + h) * HDIM + d) * SEQ + sz] = o16;
        } else {
          unsigned short* dst = (z == 0) ? qout : kout;
          dst[(((size_t)b * NH + h) * SEQ + s) * HDIM + d] = o16;
        }
      }
}

// ---------------- flash attention: 8 waves = 2 key-halves x 4 q-subtiles (R15-proven) ----------------
// VALU-lean body: Q prescaled (no per-score mul), static softmax max (|s|<~1.5, no
// overflow), denominator via ones-MFMA (matrix pipe), P->bf16 via v_cvt_pk_bf16_f32,
// NO cross-lane exchange (V^T key columns pre-swizzled to match P's natural layout).
// R17 addition: T5 s_setprio(1) around MFMA clusters (scheduler hint, zero semantic risk).
__global__ __launch_bounds__(512, 4) void attn(
    const unsigned short* __restrict__ Q,   // [BH][S][64], prescaled by C1
    const unsigned short* __restrict__ K,   // [BH][S][64]
    const unsigned short* __restrict__ VT,  // [BH][64][S], key-swizzled
    float* __restrict__ out)                // [B][S][1024]
{
  __shared__ __align__(16) unsigned char ldsraw[34816];  // staging 32KB | merge (aliased)
  const int g = blockIdx.x;                  // 512 blocks
  const int xcd = g & 7, j0 = g >> 3;        // XCD heuristic: 4 heads per XCD group
  const int bh = xcd * 4 + (j0 >> 4);
  const int qt = j0 & 15;                    // q-tile (128 queries)
  const int b = bh >> 4, h = bh & 15;
  const int tid = threadIdx.x;
  const int half = tid >> 8;                 // key-half
  const int wv4 = (tid >> 6) & 3;            // q-subtile within tile
  const int l = tid & 63;
  const int q = l & 31;                      // query column AND key/d row index
  const int hh = l >> 5;
  const int q0 = qt * 128 + wv4 * 32;
  const int NBLK = (SEQ / 2) / 32;           // 32 stages per wave

  unsigned short* kv0 = (unsigned short*)ldsraw + half * 8192;
  unsigned short* kv1 = kv0 + 4096;

  const unsigned short* Qp = Q + ((size_t)bh * SEQ + q0) * HDIM;
  const unsigned short* Kp = K + ((size_t)bh * SEQ + (size_t)half * (SEQ / 2)) * HDIM;
  const unsigned short* Vp = VT + (size_t)bh * HDIM * SEQ + (size_t)half * (SEQ / 2);

  bf16x8 qf[4];   // Q as B-operand: B[k=d][col=q], d = c*16 + hh*8 + j
#pragma unroll
  for (int c = 0; c < 4; ++c)
    qf[c] = *(const bf16x8*)(Qp + q * HDIM + c * 16 + hh * 8);

  // ones A-fragment for the denominator MFMA
  uint4 onesu = make_uint4(0x3F803F80u, 0x3F803F80u, 0x3F803F80u, 0x3F803F80u);
  bf16x8 onesf = __builtin_bit_cast(bf16x8, onesu);

  f32x16 oa = {}, ob = {}, ls = {};
  const bool maskh = (qt == 0) && (wv4 == 0) && (half == 0);
  const bool maskt = (qt == 15) && (wv4 == 3) && (half == 1);

  // Stage one 32-key tile (K 4KB + V 4KB) cooperatively across the half's 4 waves.
  auto stage = [&](unsigned short* buf, int kbase) {
    __builtin_amdgcn_global_load_lds(
        (const __attribute__((address_space(1))) void*)(Kp + (size_t)(kbase + q) * HDIM + wv4 * 16 + hh * 8),
        (__attribute__((address_space(3))) void*)(buf + wv4 * 512), 16, 0, 0);
    __builtin_amdgcn_global_load_lds(
        (const __attribute__((address_space(1))) void*)(Vp + (size_t)((wv4 >> 1) * 32 + q) * SEQ + kbase + (wv4 & 1) * 16 + hh * 8),
        (__attribute__((address_space(3))) void*)(buf + 2048 + wv4 * 512), 16, 0, 0);
  };

  auto body = [&](const bf16x8* kf, const bf16x8* vf, int t) {
    f32x16 s = {};
    __builtin_amdgcn_s_setprio(1);
#pragma unroll
    for (int c = 0; c < 4; ++c)
      s = __builtin_amdgcn_mfma_f32_32x32x16_bf16(kf[c], qf[c], s, 0, 0, 0);
    __builtin_amdgcn_s_setprio(0);
    // corner mask (scores already in log2 domain; exp2(-1e30) = 0)
    if (maskh && t == 0 && q < 8) {
      s[0] = -1e30f; s[1] = -1e30f; s[2] = -1e30f; s[3] = -1e30f;
    }
    if (maskt && t == NBLK - 1 && q >= 24) {
      s[12] = -1e30f; s[13] = -1e30f; s[14] = -1e30f; s[15] = -1e30f;
    }
    float e[16];
#pragma unroll
    for (int jj = 0; jj < 16; ++jj)
      e[jj] = __builtin_amdgcn_exp2f(s[jj]);
    // P -> bf16 pairs via hardware pack (RNE): lo = e[2jj], hi = e[2jj+1]
    unsigned int P[8];
#pragma unroll
    for (int jj = 0; jj < 8; ++jj)
      asm("v_cvt_pk_bf16_f32 %0, %1, %2" : "=v"(P[jj]) : "v"(e[2 * jj]), "v"(e[2 * jj + 1]));
    // no exchange: k-slot s holds key sigma(s) (bit2<->bit3); V^T columns pre-swizzled to match
    uint4 u0q = make_uint4(P[0], P[1], P[2], P[3]);
    uint4 u1q = make_uint4(P[4], P[5], P[6], P[7]);
    bf16x8 pb0 = __builtin_bit_cast(bf16x8, u0q);
    bf16x8 pb1 = __builtin_bit_cast(bf16x8, u1q);
    __builtin_amdgcn_s_setprio(1);
    oa = __builtin_amdgcn_mfma_f32_32x32x16_bf16(vf[0], pb0, oa, 0, 0, 0);
    oa = __builtin_amdgcn_mfma_f32_32x32x16_bf16(vf[1], pb1, oa, 0, 0, 0);
    ob = __builtin_amdgcn_mfma_f32_32x32x16_bf16(vf[2], pb0, ob, 0, 0, 0);
    ob = __builtin_amdgcn_mfma_f32_32x32x16_bf16(vf[3], pb1, ob, 0, 0, 0);
    ls = __builtin_amdgcn_mfma_f32_32x32x16_bf16(onesf, pb0, ls, 0, 0, 0);  // denom
    ls = __builtin_amdgcn_mfma_f32_32x32x16_bf16(onesf, pb1, ls, 0, 0, 0);
    __builtin_amdgcn_s_setprio(0);
  };

  // prologue: tile 0 staged and landed
  stage(kv0, 0);
  asm volatile("s_waitcnt vmcnt(0)" ::: "memory");
  __syncthreads();

  for (int t = 0; t < NBLK; ++t) {
    unsigned short* cur = (t & 1) ? kv1 : kv0;
    if (t + 1 < NBLK) stage((t & 1) ? kv0 : kv1, (t + 1) * 32);  // issue next-tile loads first
    bf16x8 kf[4], vf[4];
#pragma unroll
    for (int c = 0; c < 4; ++c) kf[c] = *(const bf16x8*)(cur + c * 512 + l * 8);
#pragma unroll
    for (int c = 0; c < 4; ++c) vf[c] = *(const bf16x8*)(cur + 2048 + c * 512 + l * 8);
    body(kf, vf, t);
    asm volatile("s_waitcnt vmcnt(0)" ::: "memory");  // next tile landed
    __syncthreads();                                   // all waves done reading cur
  }

  // denominator: every reg of ls = sum over this half's keys for query q (ones-MFMA)
  float lrt = ls[0];

  // merge halves: pure sum (static max). half 1 writes partials; half 0 combines.
  float* smf = (float*)ldsraw;   // staging fully drained by final loop sync
  if (half == 1) {
    float* p = smf + ((size_t)wv4 * 64 + l) * 33;
#pragma unroll
    for (int j = 0; j < 16; ++j) { p[j] = oa[j]; p[16 + j] = ob[j]; }
    p[32] = lrt;
  }
  __syncthreads();
  if (half == 0) {
    const float* p = smf + ((size_t)wv4 * 64 + l) * 33;
    float inv = __builtin_amdgcn_rcpf(lrt + p[32]);
    float* outp = out + ((size_t)b * SEQ + q0 + q) * EMB + h * HDIM;
#pragma unroll
    for (int qd = 0; qd < 4; ++qd) {   // regs 4qd..4qd+3 -> d = 8qd + 4hh + 0..3
      float4 sa = {(oa[4 * qd] + p[4 * qd]) * inv,
                   (oa[4 * qd + 1] + p[4 * qd + 1]) * inv,
                   (oa[4 * qd + 2] + p[4 * qd + 2]) * inv,
                   (oa[4 * qd + 3] + p[4 * qd + 3]) * inv};
      *(float4*)(outp + 8 * qd + 4 * hh) = sa;
      float4 sb = {(ob[4 * qd] + p[16 + 4 * qd]) * inv,
                   (ob[4 * qd + 1] + p[16 + 4 * qd + 1]) * inv,
                   (ob[4 * qd + 2] + p[16 + 4 * qd + 2]) * inv,
                   (ob[4 * qd + 3] + p[16 + 4 * qd + 3]) * inv};
      *(float4*)(outp + 32 + 8 * qd + 4 * hh) = sb;
    }
  }
}

extern "C" void kernel_launch(void* const* d_in, const int* in_sizes, int n_in,
                              void* d_out, int out_size, void* d_ws, size_t ws_size,
                              hipStream_t stream) {
  const float* x  = (const float*)d_in[0];
  const float* Wq = (const float*)d_in[1];
  const float* bq = (const float*)d_in[2];
  const float* Wk = (const float*)d_in[3];
  const float* bk = (const float*)d_in[4];
  const float* Wv = (const float*)d_in[5];
  const float* bv = (const float*)d_in[6];
  // d_in[7] = global_bias: per-head scalar, uniform over key axis -> softmax-invariant, dropped.
  float* out = (float*)d_out;

  char* ws = (char*)d_ws;
  unsigned short* xb   = (unsigned short*)(ws);
  unsigned short* wb   = (unsigned short*)(ws + (8u  << 20));
  unsigned short* qb   = (unsigned short*)(ws + (14u << 20));
  unsigned short* kbuf = (unsigned short*)(ws + (22u << 20));
  unsigned short* vtb  = (unsigned short*)(ws + (30u << 20));

  cvt_all<<<7168, 256, 0, stream>>>(x, Wq, Wk, Wv, xb, wb);
  qkv_gemm<<<dim3(768), 256, 0, stream>>>(xb, wb, bq, bk, bv, qb, kbuf, vtb);
  attn<<<dim3(512), 512, 0, stream>>>(qb, kbuf, vtb, out);
}